// Round 5
// baseline (302.676 us; speedup 1.0000x reference)
//
#include <hip/hip_runtime.h>

// KinematicWaveRouting: the reference recurrence
//   Q[j] <- max(Q[j] - CFL*(Q[j]-Q[j-1]) + u(t), 0),  CFL = 0.9, Q[0] = 0
// is linear (all terms nonnegative => max never binds). Outlet (Q[20]) is a
// causal FIR: outlet(t) = basin_area*50 * sum_k w[k]*runoff(t-k), K=32 taps.
//
// R6 -> R7: the cross-round invariant was VGPR_Count=32 (launch_bounds(256)
// made the allocator target 8 waves/SIMD). The FIR chains are strict fmaf
// dependencies consuming the window BACKWARDS (first tap needs the c=8
// quad), so with 32 regs the compiler can hold ~3 of 9 loads in flight ->
// serial load/wait/FMA ladder, latency exposed ~9x per group. That explains
// the monotone R3->R4->R6 slowdown as re-reads moved to slower tiers
// (VALUBusy 34->25->20%, conflicts 0 in R6, HBM 1.6 TB/s: latency-bound).
// Fix: __launch_bounds__(256,4) -> 128-VGPR budget (4 blocks/CU), and hoist
// ALL 18 window loads (both output groups) into registers before compute,
// issuing latest-consumed quads first. One latency exposure per wave,
// covered by 16 waves/CU.

#define KTAPS 32
#define TPB   256
#define TILE_T 2048                  // t-values per block (512 output quads)

struct WTab { float w[KTAPS]; };

__global__ __launch_bounds__(TPB, 4) void kwr_fir_kernel(
    const float* __restrict__ runoff,
    const float* __restrict__ basin_area,
    float* __restrict__ out,
    int T, int tiles_per_row, WTab wt)
{
    const int tid  = threadIdx.x;
    const int lane = tid & 63;
    const int wv   = tid >> 6;
    const int blk  = blockIdx.x;
    const int b    = blk / tiles_per_row;
    const int tile = blk - b * tiles_per_row;
    const long long rowbase = (long long)b * T;

    const float s = basin_area[b] * 50.0f;   // (1e6/1000/3600/20) * DT

    const float4* grow = (const float4*)(runoff + rowbase);
    float4*       orow = (float4*)(out + rowbase);
    const int qbase = tile * (TILE_T / 4);

    // Output quads: j0 = qbase + 128*wv + lane, j1 = j0 + 64.
    // Window for quad j: input quads j-8..j (win[m] = x[4*(j-8)+m], m=0..35);
    // output float r of quad j: taps k use win[32 + r - k].
    const int j0 = qbase + 128 * wv + lane;
    const int j1 = j0 + 64;

    // ---- issue ALL window loads up front, latest-consumed (c=8) first ----
    float4 v0[9], v1[9];
    if (qbase + 128 * wv >= 8) {          // wave-uniform fast path (no halo)
        #pragma unroll
        for (int c = 8; c >= 0; --c) v0[c] = grow[j0 - 8 + c];
    } else {                              // first wave of row: t<0 -> 0
        #pragma unroll
        for (int c = 8; c >= 0; --c) {
            int q = j0 - 8 + c;
            v0[c] = (q >= 0) ? grow[q] : make_float4(0.f, 0.f, 0.f, 0.f);
        }
    }
    #pragma unroll
    for (int c = 8; c >= 0; --c) v1[c] = grow[j1 - 8 + c];  // j1-8+c >= 56

    const float ss = s;

    // ---- group 0 ----------------------------------------------------------
    {
        float win[36];
        #pragma unroll
        for (int c = 0; c < 9; ++c) {
            win[4*c+0] = v0[c].x; win[4*c+1] = v0[c].y;
            win[4*c+2] = v0[c].z; win[4*c+3] = v0[c].w;
        }
        float a0 = 0.f, a1 = 0.f, a2 = 0.f, a3 = 0.f;
        #pragma unroll
        for (int k = 0; k < KTAPS; ++k) {
            const float wk = wt.w[k];
            a0 = fmaf(wk, win[32 - k], a0);
            a1 = fmaf(wk, win[33 - k], a1);
            a2 = fmaf(wk, win[34 - k], a2);
            a3 = fmaf(wk, win[35 - k], a3);
        }
        orow[j0] = make_float4(a0 * ss, a1 * ss, a2 * ss, a3 * ss);
    }

    // ---- group 1 ----------------------------------------------------------
    {
        float win[36];
        #pragma unroll
        for (int c = 0; c < 9; ++c) {
            win[4*c+0] = v1[c].x; win[4*c+1] = v1[c].y;
            win[4*c+2] = v1[c].z; win[4*c+3] = v1[c].w;
        }
        float a0 = 0.f, a1 = 0.f, a2 = 0.f, a3 = 0.f;
        #pragma unroll
        for (int k = 0; k < KTAPS; ++k) {
            const float wk = wt.w[k];
            a0 = fmaf(wk, win[32 - k], a0);
            a1 = fmaf(wk, win[33 - k], a1);
            a2 = fmaf(wk, win[34 - k], a2);
            a3 = fmaf(wk, win[35 - k], a3);
        }
        orow[j1] = make_float4(a0 * ss, a1 * ss, a2 * ss, a3 * ss);
    }
}

extern "C" void kernel_launch(void* const* d_in, const int* in_sizes, int n_in,
                              void* d_out, int out_size, void* d_ws, size_t ws_size,
                              hipStream_t stream)
{
    const float* runoff     = (const float*)d_in[0];
    const float* basin_area = (const float*)d_in[1];
    float* out = (float*)d_out;

    const int B = in_sizes[1];            // basin_area has B elements
    const int T = in_sizes[0] / B;        // runoff is (B, T)

    // Impulse response of the linear recurrence, computed in double.
    WTab wt;
    double Q[21];
    for (int j = 0; j <= 20; ++j) Q[j] = (j >= 1) ? 1.0 : 0.0;
    wt.w[0] = 1.0f;
    for (int k = 1; k < KTAPS; ++k) {
        for (int j = 20; j >= 1; --j) Q[j] = 0.1 * Q[j] + 0.9 * Q[j - 1];
        wt.w[k] = (float)Q[20];
    }

    const int tiles_per_row = T / TILE_T;           // 4096 / 2048 = 2
    const int nblk = B * tiles_per_row;             // 16384

    kwr_fir_kernel<<<nblk, TPB, 0, stream>>>(runoff, basin_area, out,
                                             T, tiles_per_row, wt);
}

// Round 6
// 233.819 us; speedup vs baseline: 1.2945x; 1.2945x over previous
//
#include <hip/hip_runtime.h>

// KinematicWaveRouting: the reference recurrence
//   Q[j] <- max(Q[j] - CFL*(Q[j]-Q[j-1]) + u(t), 0),  CFL = 0.9, Q[0] = 0
// is linear (all terms nonnegative => max never binds). Outlet (Q[20]) is a
// causal FIR: outlet(t) = basin_area*50 * sum_k w[k]*runoff(t-k), with
// w[k] = P(Binom(k,0.9) <= 19). w[k]=1 for k<=19, ~10x decay per step after
// k~21; K=32 taps => truncation error << threshold.
//
// R8 = exact revert to the best-measured structure (R2, ~75us kernel /
// 233.9us total: LDS tile + XOR-swizzled b128 reads + 8 outputs/thread)
// plus ONE orthogonal change: taps 0..19 are exactly 1.0, so the first 20
// taps form a box sum computed once and SLID across the thread's 8 outputs
// (S(r+1) = S(r) + buf[r+33] - buf[r+13]; nonneg same-magnitude terms, no
// cancellation). VALU ops/thread ~264 -> ~145. Rationale: R3-R7 structural
// rewrites all regressed (84/100/128/144us) while dur*VALUBusy stayed
// ~26us const -- fixed VALU work, growing stalls. Revert memory structure
// to the empirical best; cut the fixed VALU work instead.

#define KTAPS 32
#define RPT   8                      // outputs per thread along t
#define TPB   256
#define TILE_T (TPB * RPT)           // 2048 t-values per block
#define NQ   ((TILE_T + KTAPS) / 4)  // 520 staged quads (16B) incl. 32-halo

struct WTab { float w[KTAPS]; };

__device__ __forceinline__ int swz(int q) { return q ^ ((q >> 3) & 7); }

__global__ __launch_bounds__(TPB) void kwr_fir_lds_kernel(
    const float* __restrict__ runoff,
    const float* __restrict__ basin_area,
    float* __restrict__ out,
    int T, int tiles_per_row, WTab wt)
{
    __shared__ float4 lds[NQ];

    const int tid  = threadIdx.x;
    const int blk  = blockIdx.x;
    const int b    = blk / tiles_per_row;
    const int tile = blk - b * tiles_per_row;
    const long long rowbase = (long long)b * T;
    const int tstart = tile * TILE_T - KTAPS;  // global t of LDS float j=0

    // ---- stage unique tile bytes (coalesced float4, swizzled LDS write) ----
    const float4* gsrc = (const float4*)(runoff + rowbase + tstart);
    #pragma unroll
    for (int pass = 0; pass < 3; ++pass) {     // 256*3 >= 520
        int q = tid + pass * TPB;
        if (q < NQ) {
            float4 v;
            if (tstart + 4 * q >= 0) v = gsrc[q];          // in-row (halo ok)
            else                     v = make_float4(0.f, 0.f, 0.f, 0.f);
            lds[swz(q)] = v;
        }
    }
    __syncthreads();

    // ---- window from LDS: quads 2*tid .. 2*tid+9 (floats 8*tid..8*tid+39) --
    float buf[RPT + KTAPS];
    #pragma unroll
    for (int c = 0; c < (RPT + KTAPS) / 4; ++c) {
        float4 v = lds[swz(2 * tid + c)];
        buf[4*c+0] = v.x; buf[4*c+1] = v.y;
        buf[4*c+2] = v.z; buf[4*c+3] = v.w;
    }

    // out(t0+r) = sum_k w[k]*x(t0+r-k); output r lives at buf index 32+r,
    // tap k reads buf[32+r-k].
    //   k = 0..19 : w == 1.0 exactly  -> box sum over buf[r+13 .. r+32],
    //               computed once for r=0 and slid for r=1..7.
    //   k = 20..31: weighted taps     -> buf[r+1 .. r+12].
    float acc[RPT];
    {
        float S = 0.0f;
        #pragma unroll
        for (int m = 13; m <= 32; ++m) S += buf[m];
        acc[0] = S;
        #pragma unroll
        for (int r = 1; r < RPT; ++r) {
            S += buf[r + 32] - buf[r + 12];
            acc[r] = S;
        }
    }
    #pragma unroll
    for (int k = 20; k < KTAPS; ++k) {
        const float wk = wt.w[k];
        #pragma unroll
        for (int r = 0; r < RPT; ++r)
            acc[r] = fmaf(wk, buf[32 + r - k], acc[r]);
    }

    const float s = basin_area[b] * 50.0f;   // (1e6/1000/3600/20) * DT
    float* orow = out + rowbase + tile * TILE_T + tid * RPT;
    ((float4*)orow)[0] = make_float4(acc[0]*s, acc[1]*s, acc[2]*s, acc[3]*s);
    ((float4*)orow)[1] = make_float4(acc[4]*s, acc[5]*s, acc[6]*s, acc[7]*s);
}

extern "C" void kernel_launch(void* const* d_in, const int* in_sizes, int n_in,
                              void* d_out, int out_size, void* d_ws, size_t ws_size,
                              hipStream_t stream)
{
    const float* runoff     = (const float*)d_in[0];
    const float* basin_area = (const float*)d_in[1];
    float* out = (float*)d_out;

    const int B = in_sizes[1];            // basin_area has B elements
    const int T = in_sizes[0] / B;        // runoff is (B, T)

    // Impulse response of the linear recurrence, computed in double.
    WTab wt;
    double Q[21];
    for (int j = 0; j <= 20; ++j) Q[j] = (j >= 1) ? 1.0 : 0.0;
    wt.w[0] = 1.0f;
    for (int k = 1; k < KTAPS; ++k) {
        for (int j = 20; j >= 1; --j) Q[j] = 0.1 * Q[j] + 0.9 * Q[j - 1];
        wt.w[k] = (float)Q[20];
    }

    const int tiles_per_row = T / TILE_T;           // 4096 / 2048 = 2
    const int nblk = B * tiles_per_row;             // 16384

    kwr_fir_lds_kernel<<<nblk, TPB, 0, stream>>>(runoff, basin_area, out,
                                                 T, tiles_per_row, wt);
}